// Round 5
// baseline (337.729 us; speedup 1.0000x reference)
//
#include <hip/hip_runtime.h>
#include <hip/hip_bf16.h>
#include <math.h>

#define C_CLASSES 100000
#define EMBED     384
#define BATCH     512
#define S_SCALE   64.0f
#define COS_M_    0.8775825618903728f
#define SIN_M_    0.479425538604203f
#define TH_       (-0.8775825618903728f)
#define MM_       0.2397127693021015f
#define EPS_      1e-7f
#define LOG2E_    1.4426950408889634f
#define LN2_      0.6931471805599453f
#define BIGZ_     92.33261191693459f      /* 64 * log2(e) */

#define CT    64
#define NCH   1563                 // ceil(100000/64)
#define NBLK  256                  // persistent blocks; chunk = blk + NBLK*k

typedef __attribute__((ext_vector_type(8))) short bf16x8;
typedef __attribute__((ext_vector_type(4))) float f32x4;

__device__ inline ushort f2bf(float f) {
    unsigned u = __float_as_uint(f);
    unsigned r = (u + 0x7fffu + ((u >> 16) & 1u)) >> 16;   // RNE
    return (ushort)r;
}

// ---------------------------------------------------------------------------
// Kernel 0: convert E to bf16, packed in MFMA A-fragment order:
//   eP[((tile*12 + ks)*64 + lane)*8 + j] = bf16(E[tile*16 + (lane&15)]
//                                               [ks*32 + (lane>>4)*8 + j])
// ---------------------------------------------------------------------------
__global__ __launch_bounds__(256)
void cvt_pack_e(const float* __restrict__ emb, ushort* __restrict__ eP)
{
    int t = blockIdx.x * 256 + threadIdx.x;      // 0 .. 24575
    int lane = t & 63;
    int grp  = t >> 6;                           // tile*12 + ks
    int tile = grp / 12, ks = grp % 12;
    int lr = lane & 15, lg = lane >> 4;
    int row = tile * 16 + lr;
    int col = ks * 32 + lg * 8;
    const float4* src = (const float4*)(emb + (size_t)row * EMBED + col);
    float4 v0 = src[0], v1 = src[1];
    ushort4 o0, o1;
    o0.x = f2bf(v0.x); o0.y = f2bf(v0.y); o0.z = f2bf(v0.z); o0.w = f2bf(v0.w);
    o1.x = f2bf(v1.x); o1.y = f2bf(v1.y); o1.z = f2bf(v1.z); o1.w = f2bf(v1.w);
    ((ushort4*)eP)[t * 2]     = o0;
    ((ushort4*)eP)[t * 2 + 1] = o1;
}

// ---------------------------------------------------------------------------
// Kernel A: persistent blocks; DMA (global_load_lds) prefetch of raw fp32 W
// into LDS Raw, normalize Raw -> bf16 swizzled Wl, MFMA, fixed-max online LSE.
// grid = 256 x 1024 threads (16 waves, 1 block/CU, LDS 147 KB).
// ---------------------------------------------------------------------------
__global__ void __launch_bounds__(1024)
__attribute__((amdgpu_waves_per_eu(4, 4)))
arc_main(const ushort* __restrict__ eP, const int* __restrict__ labels,
         const float* __restrict__ weight,
         float* __restrict__ psum, float* __restrict__ zlabel)
{
    __shared__ float  Raw[CT * EMBED];     // 98304 B raw fp32 staging
    __shared__ ushort Wl[CT * EMBED];      // 49152 B bf16, XOR-swizzled

    const int tid = threadIdx.x;
    const int blk = blockIdx.x;
    const int nch = 6 + ((blk < (NCH - 6 * NBLK)) ? 1 : 0);   // 27 blocks do 7

    const int wid = tid >> 6, l = tid & 63;
    const int lr  = l & 15,  lg = l >> 4;
    const int c   = tid >> 4;      // class within chunk (0..63) = wid*4 + lg
    const int p   = tid & 15;      // 16 lanes per class

    // DMA stage: wave wid loads its own 4 rows (6144 B) of a chunk into Raw
    auto stage_rows = [&](int ch_s) {
        size_t base = (size_t)ch_s * (CT * EMBED) + (size_t)wid * 1536;
        const size_t limit = (size_t)C_CLASSES * EMBED - 4;
        #pragma unroll
        for (int j = 0; j < 6; ++j) {
            size_t off = base + j * 256 + l * 4;      // dword offset
            if (off > limit) off = limit;             // tail clamp (in-bounds)
            const __attribute__((address_space(1))) unsigned int* gp =
                (const __attribute__((address_space(1))) unsigned int*)weight + off;
            __attribute__((address_space(3))) unsigned int* lp =
                (__attribute__((address_space(3))) unsigned int*)
                    (Raw + wid * 1536 + j * 256);
            __builtin_amdgcn_global_load_lds(gp, lp, 16, 0, 0);
        }
    };

    // normalize chunk in Raw -> bf16 swizzled Wl; optionally issue next DMA
    auto normalize_chunk = [&](int ch_n, bool do_stage, int ch_s) {
        const bool val = (ch_n * CT + c) < C_CLASSES;
        float4 v[6];
        #pragma unroll
        for (int i = 0; i < 6; ++i) {
            int qq = ((p + c) & 15) + 16 * i;         // rotated: no bank clash
            v[i] = *(const float4*)&Raw[c * EMBED + qq * 4];
        }
        float ss = 0.f;
        #pragma unroll
        for (int i = 0; i < 6; ++i)
            ss += v[i].x * v[i].x + v[i].y * v[i].y
                + v[i].z * v[i].z + v[i].w * v[i].w;   // consumes all reads
        __builtin_amdgcn_sched_barrier(0);
        if (do_stage) stage_rows(ch_s);                // Raw reads are done
        __builtin_amdgcn_sched_barrier(0);
        #pragma unroll
        for (int d = 1; d < 16; d <<= 1) ss += __shfl_xor(ss, d, 64);
        const float inv = (val && ss > 0.f) ? rsqrtf(ss) : 0.f;
        #pragma unroll
        for (int i = 0; i < 6; ++i) {
            int qq  = ((p + c) & 15) + 16 * i;
            int idx = c * EMBED + qq * 4;
            ushort4 o;
            o.x = f2bf(v[i].x * inv); o.y = f2bf(v[i].y * inv);
            o.z = f2bf(v[i].z * inv); o.w = f2bf(v[i].w * inv);
            *(ushort4*)&Wl[idx ^ ((c & 7) << 3)] = o;
        }
    };

    // labels for the 8 rows this thread's accumulators own
    int labr[8];
    #pragma unroll
    for (int q = 0; q < 8; ++q)
        labr[q] = labels[wid * 32 + (q >> 2) * 16 + lg * 4 + (q & 3)];

    float s_l[8];
    #pragma unroll
    for (int q = 0; q < 8; ++q) s_l[q] = 0.f;

    const ushort* abase = eP + ((size_t)(wid * 2) * 12 * 64 + l) * 8;

    // ---- prologue: stage chunk0, normalize it, start chunk1 DMA ----
    stage_rows(blk);
    asm volatile("s_waitcnt vmcnt(0)" ::: "memory");
    __builtin_amdgcn_sched_barrier(0);
    normalize_chunk(blk, nch > 1, blk + NBLK);
    asm volatile("s_waitcnt lgkmcnt(0)" ::: "memory");
    __builtin_amdgcn_s_barrier();

    int ch = blk;
    for (int k = 0; k < nch; ++k) {
        const int c0 = ch * CT;

        // ---- MFMA: wave covers 2 M-tiles x 4 N-tiles, K=384 ----
        f32x4 acc[2][4];
        #pragma unroll
        for (int mt = 0; mt < 2; ++mt)
            #pragma unroll
            for (int nt = 0; nt < 4; ++nt)
                acc[mt][nt] = (f32x4){0.f, 0.f, 0.f, 0.f};

        #pragma unroll
        for (int ks = 0; ks < 12; ++ks) {
            bf16x8 a0 = *(const bf16x8*)(abase + ks * 512);
            bf16x8 a1 = *(const bf16x8*)(abase + (12 + ks) * 512);
            bf16x8 b[4];
            #pragma unroll
            for (int nt = 0; nt < 4; ++nt) {
                int cc  = nt * 16 + lr;
                int idx = cc * EMBED + ks * 32 + lg * 8;
                b[nt] = *(const bf16x8*)&Wl[idx ^ ((cc & 7) << 3)];
            }
            #pragma unroll
            for (int nt = 0; nt < 4; ++nt) {
                acc[0][nt] = __builtin_amdgcn_mfma_f32_16x16x32_bf16(
                    a0, b[nt], acc[0][nt], 0, 0, 0);
                acc[1][nt] = __builtin_amdgcn_mfma_f32_16x16x32_bf16(
                    a1, b[nt], acc[1][nt], 0, 0, 0);
            }
        }

        // ---- epilogue: margin + fixed-max LSE accumulation ----
        #pragma unroll
        for (int mt = 0; mt < 2; ++mt) {
            #pragma unroll
            for (int rg = 0; rg < 4; ++rg) {
                const int lab = labr[mt * 4 + rg];
                float acc4 = 0.f;
                #pragma unroll
                for (int nt = 0; nt < 4; ++nt) {
                    int gc = c0 + nt * 16 + lr;
                    float cosv = acc[mt][nt][rg];
                    cosv = fminf(fmaxf(cosv, -1.f + EPS_), 1.f - EPS_);
                    float zz = S_SCALE * cosv;
                    if (gc == lab) {
                        float zm;
                        if (cosv > TH_) {
                            float sv = sqrtf(fmaxf(1.f - cosv * cosv, 0.f));
                            zm = S_SCALE * (cosv * COS_M_ - sv * SIN_M_);
                        } else {
                            zm = S_SCALE * (cosv - MM_);
                        }
                        zlabel[wid * 32 + mt * 16 + lg * 4 + rg] = zm;
                        zz = zm;
                    }
                    float z = (gc >= C_CLASSES) ? -1e30f
                                                : zz * LOG2E_ - BIGZ_;
                    acc4 += exp2f(z);
                }
                s_l[mt * 4 + rg] += acc4;
            }
        }

        // ---- pipeline turn: normalize chunk k+1, issue DMA for k+2 ----
        if (k + 1 < nch) {
            __builtin_amdgcn_s_barrier();                 // Wl readers done
            asm volatile("s_waitcnt vmcnt(0)" ::: "memory");  // Raw landed
            __builtin_amdgcn_sched_barrier(0);
            normalize_chunk(ch + NBLK, k + 2 < nch, ch + 2 * NBLK);
            asm volatile("s_waitcnt lgkmcnt(0)" ::: "memory");
            __builtin_amdgcn_s_barrier();                 // Wl ready
        }
        ch += NBLK;
    }

    // ---- merge the 16 class-column lanes per row; one partial per block ----
    #pragma unroll
    for (int q = 0; q < 8; ++q) {
        float s = s_l[q];
        #pragma unroll
        for (int d = 1; d < 16; d <<= 1) s += __shfl_xor(s, d, 64);
        if (lr == 0) {
            int r = wid * 32 + (q >> 2) * 16 + lg * 4 + (q & 3);
            psum[(size_t)r * NBLK + blk] = s;
        }
    }
}

// ---------------------------------------------------------------------------
// Kernel B: sum 256 block-partials per row -> row loss
// ---------------------------------------------------------------------------
__global__ __launch_bounds__(256)
void arc_reduce(const float* __restrict__ psum, const float* __restrict__ zlabel,
                float* __restrict__ rowloss)
{
    const int r = blockIdx.x;
    const int tid = threadIdx.x;
    float s = psum[(size_t)r * NBLK + tid];
    #pragma unroll
    for (int d = 1; d < 64; d <<= 1) s += __shfl_xor(s, d, 64);
    __shared__ float ssh[4];
    if ((tid & 63) == 0) ssh[tid >> 6] = s;
    __syncthreads();
    if (tid == 0) {
        float t = ssh[0] + ssh[1] + ssh[2] + ssh[3];
        rowloss[r] = LN2_ * (BIGZ_ + log2f(t)) - zlabel[r];
    }
}

// ---------------------------------------------------------------------------
// Kernel C: mean over rows
// ---------------------------------------------------------------------------
__global__ __launch_bounds__(512)
void arc_mean(const float* __restrict__ rowloss, float* __restrict__ out)
{
    const int tid = threadIdx.x;
    float v = rowloss[tid];
    #pragma unroll
    for (int d = 1; d < 64; d <<= 1) v += __shfl_xor(v, d, 64);
    __shared__ float sv[8];
    if ((tid & 63) == 0) sv[tid >> 6] = v;
    __syncthreads();
    if (tid == 0) {
        float t = 0.f;
        #pragma unroll
        for (int w = 0; w < 8; ++w) t += sv[w];
        out[0] = t / (float)BATCH;
    }
}

extern "C" void kernel_launch(void* const* d_in, const int* in_sizes, int n_in,
                              void* d_out, int out_size, void* d_ws, size_t ws_size,
                              hipStream_t stream)
{
    (void)in_sizes; (void)n_in; (void)out_size; (void)ws_size;
    const float* emb    = (const float*)d_in[0];
    const int*   labels = (const int*)d_in[1];
    const float* weight = (const float*)d_in[2];
    float* out = (float*)d_out;

    float* psum    = (float*)d_ws;                    // [BATCH][NBLK]
    float* zlabel  = psum + (size_t)BATCH * NBLK;     // [BATCH]
    float* rowloss = zlabel + BATCH;                  // [BATCH]
    ushort* eP     = (ushort*)(rowloss + BATCH);      // packed bf16 E fragments

    cvt_pack_e<<<(BATCH * EMBED / 8) / 256, 256, 0, stream>>>(emb, eP);
    arc_main<<<NBLK, 1024, 0, stream>>>(eP, labels, weight, psum, zlabel);
    arc_reduce<<<BATCH, 256, 0, stream>>>(psum, zlabel, rowloss);
    arc_mean<<<1, 512, 0, stream>>>(rowloss, out);
}

// Round 6
// 133.555 us; speedup vs baseline: 2.5288x; 2.5288x over previous
//
#include <hip/hip_runtime.h>
#include <hip/hip_bf16.h>
#include <math.h>

#define C_CLASSES 100000
#define EMBED     384
#define BATCH     512
#define S_SCALE   64.0f
#define COS_M_    0.8775825618903728f
#define SIN_M_    0.479425538604203f
#define TH_       (-0.8775825618903728f)
#define MM_       0.2397127693021015f
#define EPS_      1e-7f
#define LOG2E_    1.4426950408889634f
#define LN2_      0.6931471805599453f
#define BIGZ_     92.33261191693459f      /* 64 * log2(e) */

#define CT    64
#define NCH   1563                         // ceil(100000/64)
#define WTILES 6252                        // 6250 real 16-class tiles + 2 pad

typedef __attribute__((ext_vector_type(8))) short bf16x8;
typedef __attribute__((ext_vector_type(4))) float f32x4;

__device__ inline ushort f2bf(float f) {
    unsigned u = __float_as_uint(f);
    unsigned r = (u + 0x7fffu + ((u >> 16) & 1u)) >> 16;   // RNE
    return (ushort)r;
}

// ---------------------------------------------------------------------------
// Kernel 0: convert E to bf16, packed in MFMA A-fragment order:
//   eP[((tile*12 + ks)*64 + lane)*8 + j] = bf16(E[tile*16 + (lane&15)]
//                                               [ks*32 + (lane>>4)*8 + j])
// ---------------------------------------------------------------------------
__global__ __launch_bounds__(256)
void cvt_pack_e(const float* __restrict__ emb, ushort* __restrict__ eP)
{
    int t = blockIdx.x * 256 + threadIdx.x;      // 0 .. 24575
    int lane = t & 63;
    int grp  = t >> 6;                           // tile*12 + ks
    int tile = grp / 12, ks = grp % 12;
    int lr = lane & 15, lg = lane >> 4;
    int row = tile * 16 + lr;
    int col = ks * 32 + lg * 8;
    const float4* src = (const float4*)(emb + (size_t)row * EMBED + col);
    float4 v0 = src[0], v1 = src[1];
    ushort4 o0, o1;
    o0.x = f2bf(v0.x); o0.y = f2bf(v0.y); o0.z = f2bf(v0.z); o0.w = f2bf(v0.w);
    o1.x = f2bf(v1.x); o1.y = f2bf(v1.y); o1.z = f2bf(v1.z); o1.w = f2bf(v1.w);
    ((ushort4*)eP)[t * 2]     = o0;
    ((ushort4*)eP)[t * 2 + 1] = o1;
}

// ---------------------------------------------------------------------------
// Kernel 1: stream W once: row-normalize in registers, write bf16 packed in
// MFMA B-fragment order:
//   wB[((cls16*12 + ks)*64 + lane)*8 + j] = bf16n(W[cls16*16 + (lane&15)]
//                                                 [ks*32 + (lane>>4)*8 + j])
// 16 lanes per row; grid = 100000/16 = 6250 blocks x 256 threads.
// ---------------------------------------------------------------------------
__global__ __launch_bounds__(256)
void norm_pack_w(const float* __restrict__ weight, ushort* __restrict__ wB)
{
    const int row = blockIdx.x * 16 + (threadIdx.x >> 4);
    const int p   = threadIdx.x & 15;
    const float4* src = (const float4*)(weight + (size_t)row * EMBED) + p;

    float4 v[6];
    float ss = 0.f;
    #pragma unroll
    for (int i = 0; i < 6; ++i) {
        v[i] = src[16 * i];
        ss += v[i].x * v[i].x + v[i].y * v[i].y
            + v[i].z * v[i].z + v[i].w * v[i].w;
    }
    #pragma unroll
    for (int d = 1; d < 16; d <<= 1) ss += __shfl_xor(ss, d, 64);
    const float inv = (ss > 0.f) ? rsqrtf(ss) : 0.f;

    const size_t tbase = ((size_t)(row >> 4) * 12) * 512 + (row & 15) * 8;
    #pragma unroll
    for (int i = 0; i < 6; ++i) {
        int q = p + 16 * i;                   // quad index 0..95 (k = 4q)
        ushort4 o;
        o.x = f2bf(v[i].x * inv); o.y = f2bf(v[i].y * inv);
        o.z = f2bf(v[i].z * inv); o.w = f2bf(v[i].w * inv);
        size_t dst = tbase + (size_t)(q >> 3) * 512
                   + (size_t)((q >> 1) & 3) * 128 + (q & 1) * 4;
        *(ushort4*)&wB[dst] = o;
    }
}

// ---------------------------------------------------------------------------
// Kernel 2: barrier-free, LDS-free MFMA GEMM + margin + fixed-max LSE.
// grid = NCH blocks x 512 threads (8 waves); wave w owns rows 64w..64w+63.
// ---------------------------------------------------------------------------
__global__ __launch_bounds__(512, 4)
void arc_gemm(const ushort* __restrict__ eP, const ushort* __restrict__ wB,
              const int* __restrict__ labels,
              float* __restrict__ psum, float* __restrict__ zlabel)
{
    const int tid = threadIdx.x;
    const int blk = blockIdx.x;
    const int c0  = blk * CT;

    const int wid = tid >> 6, l = tid & 63;
    const int lr  = l & 15,  lg = l >> 4;

    const ushort* abase = eP + ((size_t)(wid * 4) * 12 * 64 + l) * 8;
    const ushort* bbase = wB + ((size_t)(c0 >> 4) * 12 * 64 + l) * 8;

    f32x4 acc[4][4];
    #pragma unroll
    for (int mt = 0; mt < 4; ++mt)
        #pragma unroll
        for (int nt = 0; nt < 4; ++nt)
            acc[mt][nt] = (f32x4){0.f, 0.f, 0.f, 0.f};

    #pragma unroll
    for (int ks = 0; ks < 12; ++ks) {
        bf16x8 a[4], b[4];
        #pragma unroll
        for (int mt = 0; mt < 4; ++mt)
            a[mt] = *(const bf16x8*)(abase + (mt * 12 + ks) * 512);
        #pragma unroll
        for (int nt = 0; nt < 4; ++nt)
            b[nt] = *(const bf16x8*)(bbase + (nt * 12 + ks) * 512);
        #pragma unroll
        for (int mt = 0; mt < 4; ++mt)
            #pragma unroll
            for (int nt = 0; nt < 4; ++nt)
                acc[mt][nt] = __builtin_amdgcn_mfma_f32_16x16x32_bf16(
                    a[mt], b[nt], acc[mt][nt], 0, 0, 0);
    }

    // ---- epilogue: clamp, margin at label, fixed-max partial LSE ----
    #pragma unroll
    for (int mt = 0; mt < 4; ++mt) {
        #pragma unroll
        for (int rg = 0; rg < 4; ++rg) {
            const int r   = wid * 64 + mt * 16 + lg * 4 + rg;
            const int lab = labels[r];
            float acc4 = 0.f;
            #pragma unroll
            for (int nt = 0; nt < 4; ++nt) {
                int gc = c0 + nt * 16 + lr;
                float cosv = acc[mt][nt][rg];
                cosv = fminf(fmaxf(cosv, -1.f + EPS_), 1.f - EPS_);
                float zz = S_SCALE * cosv;
                if (gc == lab) {
                    float zm;
                    if (cosv > TH_) {
                        float sv = sqrtf(fmaxf(1.f - cosv * cosv, 0.f));
                        zm = S_SCALE * (cosv * COS_M_ - sv * SIN_M_);
                    } else {
                        zm = S_SCALE * (cosv - MM_);
                    }
                    zlabel[r] = zm;
                    zz = zm;
                }
                float z = (gc >= C_CLASSES) ? -1e30f : zz * LOG2E_ - BIGZ_;
                acc4 += exp2f(z);
            }
            float s = acc4;
            #pragma unroll
            for (int d = 1; d < 16; d <<= 1) s += __shfl_xor(s, d, 64);
            if (lr == 0) psum[(size_t)blk * BATCH + r] = s;
        }
    }
}

// ---------------------------------------------------------------------------
// Kernel 3: sum NCH block-partials per row -> row loss
// ---------------------------------------------------------------------------
__global__ __launch_bounds__(256)
void arc_reduce(const float* __restrict__ psum, const float* __restrict__ zlabel,
                float* __restrict__ rowloss)
{
    const int r = blockIdx.x;
    const int tid = threadIdx.x;
    float s = 0.f;
    for (int k = tid; k < NCH; k += 256)
        s += psum[(size_t)k * BATCH + r];
    #pragma unroll
    for (int d = 1; d < 64; d <<= 1) s += __shfl_xor(s, d, 64);
    __shared__ float ssh[4];
    if ((tid & 63) == 0) ssh[tid >> 6] = s;
    __syncthreads();
    if (tid == 0) {
        float t = ssh[0] + ssh[1] + ssh[2] + ssh[3];
        rowloss[r] = LN2_ * (BIGZ_ + log2f(t)) - zlabel[r];
    }
}

// ---------------------------------------------------------------------------
// Kernel 4: mean over rows
// ---------------------------------------------------------------------------
__global__ __launch_bounds__(512)
void arc_mean(const float* __restrict__ rowloss, float* __restrict__ out)
{
    const int tid = threadIdx.x;
    float v = rowloss[tid];
    #pragma unroll
    for (int d = 1; d < 64; d <<= 1) v += __shfl_xor(v, d, 64);
    __shared__ float sv[8];
    if ((tid & 63) == 0) sv[tid >> 6] = v;
    __syncthreads();
    if (tid == 0) {
        float t = 0.f;
        #pragma unroll
        for (int w = 0; w < 8; ++w) t += sv[w];
        out[0] = t / (float)BATCH;
    }
}

// ===========================================================================
// FALLBACK (small-workspace) path: round-3 fused kernel, known good @145us.
// ===========================================================================
__global__ __launch_bounds__(512, 4)
void arc_fused(const ushort* __restrict__ eP, const int* __restrict__ labels,
               const float* __restrict__ weight,
               float* __restrict__ pmax, float* __restrict__ psum,
               float* __restrict__ zlabel)
{
    __shared__ ushort Wl[CT * EMBED];
    __shared__ int    labL[BATCH];

    const int tid = threadIdx.x;
    const int blk = blockIdx.x;
    const int c0  = blk * CT;

    labL[tid] = labels[tid];

    const int c = tid >> 3, p = tid & 7;
    const bool valid = (c0 + c) < C_CLASSES;
    const float4* wrow = (const float4*)(weight + (size_t)(c0 + c) * EMBED);
    float ss = 0.f;
    #pragma unroll
    for (int i = 0; i < 12; ++i) {
        float4 v = valid ? wrow[p + 8 * i] : make_float4(0.f, 0.f, 0.f, 0.f);
        ss += v.x * v.x + v.y * v.y + v.z * v.z + v.w * v.w;
    }
    #pragma unroll
    for (int d = 1; d < 8; d <<= 1) ss += __shfl_xor(ss, d, 64);
    const float inv = (valid && ss > 0.f) ? rsqrtf(ss) : 0.f;

    #pragma unroll
    for (int i = 0; i < 12; ++i) {
        float4 v = valid ? wrow[p + 8 * i] : make_float4(0.f, 0.f, 0.f, 0.f);
        int q   = p + 8 * i;
        int idx = c * EMBED + q * 4;
        int sw  = idx ^ ((c & 7) << 3);
        ushort4 o;
        o.x = f2bf(v.x * inv); o.y = f2bf(v.y * inv);
        o.z = f2bf(v.z * inv); o.w = f2bf(v.w * inv);
        *(ushort4*)&Wl[sw] = o;
    }
    __syncthreads();

    const int wid = tid >> 6, l = tid & 63;
    const int lr = l & 15, lg = l >> 4;
    const int mbase = wid * 64;

    f32x4 acc[4][4];
    #pragma unroll
    for (int mt = 0; mt < 4; ++mt)
        #pragma unroll
        for (int nt = 0; nt < 4; ++nt)
            acc[mt][nt] = (f32x4){0.f, 0.f, 0.f, 0.f};

    const ushort* abase = eP + ((size_t)(wid * 4) * 12 * 64 + l) * 8;

    #pragma unroll
    for (int ks = 0; ks < 12; ++ks) {
        bf16x8 a[4], b[4];
        #pragma unroll
        for (int mt = 0; mt < 4; ++mt)
            a[mt] = *(const bf16x8*)(abase + (mt * 12 + ks) * 512);
        #pragma unroll
        for (int nt = 0; nt < 4; ++nt) {
            int cc  = nt * 16 + lr;
            int idx = cc * EMBED + ks * 32 + lg * 8;
            b[nt] = *(const bf16x8*)&Wl[idx ^ ((cc & 7) << 3)];
        }
        #pragma unroll
        for (int mt = 0; mt < 4; ++mt)
            #pragma unroll
            for (int nt = 0; nt < 4; ++nt)
                acc[mt][nt] = __builtin_amdgcn_mfma_f32_16x16x32_bf16(
                    a[mt], b[nt], acc[mt][nt], 0, 0, 0);
    }

    #pragma unroll
    for (int mt = 0; mt < 4; ++mt) {
        #pragma unroll
        for (int rg = 0; rg < 4; ++rg) {
            int r   = mbase + mt * 16 + lg * 4 + rg;
            int lab = labL[r];
            float z[4];
            #pragma unroll
            for (int nt = 0; nt < 4; ++nt) {
                int gc = c0 + nt * 16 + lr;
                float cosv = acc[mt][nt][rg];
                cosv = fminf(fmaxf(cosv, -1.f + EPS_), 1.f - EPS_);
                float zz = S_SCALE * cosv;
                if (gc == lab) {
                    float zm;
                    if (cosv > TH_) {
                        float sv = sqrtf(fmaxf(1.f - cosv * cosv, 0.f));
                        zm = S_SCALE * (cosv * COS_M_ - sv * SIN_M_);
                    } else {
                        zm = S_SCALE * (cosv - MM_);
                    }
                    zlabel[r] = zm;
                    zz = zm;
                }
                z[nt] = (gc >= C_CLASSES) ? -1e30f : zz * LOG2E_;
            }
            float m = fmaxf(fmaxf(z[0], z[1]), fmaxf(z[2], z[3]));
            #pragma unroll
            for (int d = 1; d < 16; d <<= 1) m = fmaxf(m, __shfl_xor(m, d, 64));
            float s = 0.f;
            #pragma unroll
            for (int nt = 0; nt < 4; ++nt) s += exp2f(z[nt] - m);
            #pragma unroll
            for (int d = 1; d < 16; d <<= 1) s += __shfl_xor(s, d, 64);
            if (lr == 0) {
                pmax[(size_t)r * NCH + blk] = m;
                psum[(size_t)r * NCH + blk] = s;
            }
        }
    }
}

__global__ __launch_bounds__(256)
void arc_reduce_m(const float* __restrict__ pmax, const float* __restrict__ psum,
                  const float* __restrict__ zlabel, float* __restrict__ rowloss)
{
    const int r = blockIdx.x;
    const int tid = threadIdx.x;
    float m = -1e30f, s = 0.f;
    for (int k = tid; k < NCH; k += 256) {
        float m2 = pmax[(size_t)r * NCH + k];
        float s2 = psum[(size_t)r * NCH + k];
        float M = fmaxf(m, m2);
        s = s * exp2f(m - M) + s2 * exp2f(m2 - M);
        m = M;
    }
    #pragma unroll
    for (int d = 1; d < 64; d <<= 1) {
        float m2 = __shfl_xor(m, d, 64);
        float s2 = __shfl_xor(s, d, 64);
        float M = fmaxf(m, m2);
        s = s * exp2f(m - M) + s2 * exp2f(m2 - M);
        m = M;
    }
    __shared__ float sm[4], ssh[4];
    if ((tid & 63) == 0) { sm[tid >> 6] = m; ssh[tid >> 6] = s; }
    __syncthreads();
    if (tid == 0) {
        m = sm[0]; s = ssh[0];
        #pragma unroll
        for (int w = 1; w < 4; ++w) {
            float M = fmaxf(m, sm[w]);
            s = s * exp2f(m - M) + ssh[w] * exp2f(sm[w] - M);
            m = M;
        }
        rowloss[r] = LN2_ * (m + log2f(s)) - zlabel[r];
    }
}

extern "C" void kernel_launch(void* const* d_in, const int* in_sizes, int n_in,
                              void* d_out, int out_size, void* d_ws, size_t ws_size,
                              hipStream_t stream)
{
    (void)in_sizes; (void)n_in; (void)out_size;
    const float* emb    = (const float*)d_in[0];
    const int*   labels = (const int*)d_in[1];
    const float* weight = (const float*)d_in[2];
    float* out = (float*)d_out;

    // main-path workspace layout
    const size_t psum_elems = (size_t)NCH * BATCH;         // 800,256
    const size_t eP_elems   = (size_t)BATCH * EMBED;       // 196,608 ushorts
    const size_t wB_elems   = (size_t)WTILES * 12 * 512;   // 38,412,288 ushorts

    float*  psum    = (float*)d_ws;
    float*  zlabel  = psum + psum_elems;
    float*  rowloss = zlabel + BATCH;
    ushort* eP      = (ushort*)(rowloss + BATCH);
    ushort* wB      = eP + eP_elems;
    const size_t need = (char*)(wB + wB_elems) - (char*)d_ws;

    if (ws_size >= need) {
        cvt_pack_e<<<(BATCH * EMBED / 8) / 256, 256, 0, stream>>>(emb, eP);
        norm_pack_w<<<C_CLASSES / 16, 256, 0, stream>>>(weight, wB);
        arc_gemm<<<NCH, 512, 0, stream>>>(eP, wB, labels, psum, zlabel);
        arc_reduce<<<BATCH, 256, 0, stream>>>(psum, zlabel, rowloss);
        arc_mean<<<1, 512, 0, stream>>>(rowloss, out);
    } else {
        // fallback: fused round-3 path (~13.6 MB workspace)
        float*  pmaxF    = (float*)d_ws;                       // [BATCH][NCH]
        float*  psumF    = pmaxF + psum_elems;                 // [BATCH][NCH]
        float*  zlabelF  = psumF + psum_elems;
        float*  rowlossF = zlabelF + BATCH;
        ushort* ePF      = (ushort*)(rowlossF + BATCH);
        cvt_pack_e<<<(BATCH * EMBED / 8) / 256, 256, 0, stream>>>(emb, ePF);
        arc_fused<<<NCH, 512, 0, stream>>>(ePF, labels, weight,
                                           pmaxF, psumF, zlabelF);
        arc_reduce_m<<<BATCH, 256, 0, stream>>>(pmaxF, psumF, zlabelF, rowlossF);
        arc_mean<<<1, 512, 0, stream>>>(rowlossF, out);
    }
}

// Round 7
// 125.414 us; speedup vs baseline: 2.6929x; 1.0649x over previous
//
#include <hip/hip_runtime.h>
#include <hip/hip_bf16.h>
#include <math.h>

#define C_CLASSES 100000
#define EMBED     384
#define BATCH     512
#define S_SCALE   64.0f
#define COS_M_    0.8775825618903728f
#define SIN_M_    0.479425538604203f
#define TH_       (-0.8775825618903728f)
#define MM_       0.2397127693021015f
#define EPS_      1e-7f
#define LOG2E_    1.4426950408889634f
#define LN2_      0.6931471805599453f
#define BIGZ_     92.33261191693459f      /* 64 * log2(e) */

#define CT    64
#define NCH   1563                         // ceil(100000/64)
#define WTILES 6252                        // 6250 real 16-class tiles + 2 pad

typedef __attribute__((ext_vector_type(8))) short bf16x8;
typedef __attribute__((ext_vector_type(4))) float f32x4;

#define AS1 __attribute__((address_space(1)))
#define AS3 __attribute__((address_space(3)))

__device__ inline ushort f2bf(float f) {
    unsigned u = __float_as_uint(f);
    unsigned r = (u + 0x7fffu + ((u >> 16) & 1u)) >> 16;   // RNE
    return (ushort)r;
}

// ---------------------------------------------------------------------------
// Kernel 0: convert E to bf16, packed in MFMA A-fragment order:
//   eP[((tile*12 + ks)*64 + lane)*8 + j] = bf16(E[tile*16 + (lane&15)]
//                                               [ks*32 + (lane>>4)*8 + j])
// ---------------------------------------------------------------------------
__global__ __launch_bounds__(256)
void cvt_pack_e(const float* __restrict__ emb, ushort* __restrict__ eP)
{
    int t = blockIdx.x * 256 + threadIdx.x;      // 0 .. 24575
    int lane = t & 63;
    int grp  = t >> 6;                           // tile*12 + ks
    int tile = grp / 12, ks = grp % 12;
    int lr = lane & 15, lg = lane >> 4;
    int row = tile * 16 + lr;
    int col = ks * 32 + lg * 8;
    const float4* src = (const float4*)(emb + (size_t)row * EMBED + col);
    float4 v0 = src[0], v1 = src[1];
    ushort4 o0, o1;
    o0.x = f2bf(v0.x); o0.y = f2bf(v0.y); o0.z = f2bf(v0.z); o0.w = f2bf(v0.w);
    o1.x = f2bf(v1.x); o1.y = f2bf(v1.y); o1.z = f2bf(v1.z); o1.w = f2bf(v1.w);
    ((ushort4*)eP)[t * 2]     = o0;
    ((ushort4*)eP)[t * 2 + 1] = o1;
}

// ---------------------------------------------------------------------------
// Kernel 1: stream W once: row-normalize in registers, write bf16 packed in
// MFMA B-fragment order. 16 lanes per row; grid = 6250 blocks x 256 threads.
// ---------------------------------------------------------------------------
__global__ __launch_bounds__(256)
void norm_pack_w(const float* __restrict__ weight, ushort* __restrict__ wB)
{
    const int row = blockIdx.x * 16 + (threadIdx.x >> 4);
    const int p   = threadIdx.x & 15;
    const float4* src = (const float4*)(weight + (size_t)row * EMBED) + p;

    float4 v[6];
    float ss = 0.f;
    #pragma unroll
    for (int i = 0; i < 6; ++i) {
        v[i] = src[16 * i];
        ss += v[i].x * v[i].x + v[i].y * v[i].y
            + v[i].z * v[i].z + v[i].w * v[i].w;
    }
    #pragma unroll
    for (int d = 1; d < 16; d <<= 1) ss += __shfl_xor(ss, d, 64);
    const float inv = (ss > 0.f) ? rsqrtf(ss) : 0.f;

    const size_t tbase = ((size_t)(row >> 4) * 12) * 512 + (row & 15) * 8;
    #pragma unroll
    for (int i = 0; i < 6; ++i) {
        int q = p + 16 * i;                   // quad index 0..95 (k = 4q)
        ushort4 o;
        o.x = f2bf(v[i].x * inv); o.y = f2bf(v[i].y * inv);
        o.z = f2bf(v[i].z * inv); o.w = f2bf(v[i].w * inv);
        size_t dst = tbase + (size_t)(q >> 3) * 512
                   + (size_t)((q >> 1) & 3) * 128 + (q & 1) * 4;
        *(ushort4*)&wB[dst] = o;
    }
}

// ---------------------------------------------------------------------------
// Kernel 2: MFMA GEMM with DMA-staged B-slice in LDS + margin + fixed-max LSE.
// grid = NCH blocks x 512 threads (8 waves); wave w owns rows 64w..64w+63.
// LDS = 48 KB (B-slice, fragment-packed linear) -> 2 blocks/CU.
// ---------------------------------------------------------------------------
__global__ __launch_bounds__(512, 4)
void arc_gemm(const ushort* __restrict__ eP, const ushort* __restrict__ wB,
              const int* __restrict__ labels,
              float* __restrict__ psum, float* __restrict__ zlabel)
{
    __shared__ ushort Bl[CT / 16 * 12 * 512];      // 24576 ushorts = 49152 B

    const int tid = threadIdx.x;
    const int blk = blockIdx.x;
    const int c0  = blk * CT;

    const int wid = tid >> 6, l = tid & 63;
    const int lr  = l & 15,  lg = l >> 4;

    // ---- DMA the block's B-slice (4 cls16-tiles, 49152 B) into LDS ----
    // layout is identical to wB (fragment-packed), so lane reads are linear.
    {
        const ushort* slice = wB + (size_t)(c0 >> 4) * 6144;
        #pragma unroll
        for (int j = 0; j < 6; ++j) {
            int chunk = j * 512 + tid;                      // 16B chunk id
            const AS1 uint* gp =
                (const AS1 uint*)((const AS1 ushort*)slice + (size_t)chunk * 8);
            AS3 uint* lp =
                (AS3 uint*)((AS3 ushort*)Bl + (size_t)(j * 512 + (tid & ~63)) * 8);
            __builtin_amdgcn_global_load_lds(gp, lp, 16, 0, 0);
        }
    }

    const ushort* abase = eP + ((size_t)(wid * 4) * 12 * 64 + l) * 8;

    __syncthreads();   // drains vmcnt(0): DMA complete, LDS visible

    f32x4 acc[4][4];
    #pragma unroll
    for (int mt = 0; mt < 4; ++mt)
        #pragma unroll
        for (int nt = 0; nt < 4; ++nt)
            acc[mt][nt] = (f32x4){0.f, 0.f, 0.f, 0.f};

    #pragma unroll
    for (int ks = 0; ks < 12; ++ks) {
        bf16x8 a[4], b[4];
        #pragma unroll
        for (int mt = 0; mt < 4; ++mt)
            a[mt] = *(const bf16x8*)(abase + (mt * 12 + ks) * 512);
        #pragma unroll
        for (int nt = 0; nt < 4; ++nt)
            b[nt] = *(const bf16x8*)&Bl[(size_t)((nt * 12 + ks) * 64 + l) * 8];
        #pragma unroll
        for (int mt = 0; mt < 4; ++mt)
            #pragma unroll
            for (int nt = 0; nt < 4; ++nt)
                acc[mt][nt] = __builtin_amdgcn_mfma_f32_16x16x32_bf16(
                    a[mt], b[nt], acc[mt][nt], 0, 0, 0);
    }

    // ---- epilogue: clamp, margin at label, fixed-max partial LSE ----
    #pragma unroll
    for (int mt = 0; mt < 4; ++mt) {
        #pragma unroll
        for (int rg = 0; rg < 4; ++rg) {
            const int r   = wid * 64 + mt * 16 + lg * 4 + rg;
            const int lab = labels[r];
            float acc4 = 0.f;
            #pragma unroll
            for (int nt = 0; nt < 4; ++nt) {
                int gc = c0 + nt * 16 + lr;
                float cosv = acc[mt][nt][rg];
                cosv = fminf(fmaxf(cosv, -1.f + EPS_), 1.f - EPS_);
                float zz = S_SCALE * cosv;
                if (gc == lab) {
                    float zm;
                    if (cosv > TH_) {
                        float sv = sqrtf(fmaxf(1.f - cosv * cosv, 0.f));
                        zm = S_SCALE * (cosv * COS_M_ - sv * SIN_M_);
                    } else {
                        zm = S_SCALE * (cosv - MM_);
                    }
                    zlabel[r] = zm;
                    zz = zm;
                }
                float z = (gc >= C_CLASSES) ? -1e30f : zz * LOG2E_ - BIGZ_;
                acc4 += exp2f(z);
            }
            float s = acc4;
            #pragma unroll
            for (int d = 1; d < 16; d <<= 1) s += __shfl_xor(s, d, 64);
            if (lr == 0) psum[(size_t)blk * BATCH + r] = s;
        }
    }
}

// ---------------------------------------------------------------------------
// Kernel 3: sum NCH block-partials per row -> row loss
// ---------------------------------------------------------------------------
__global__ __launch_bounds__(256)
void arc_reduce(const float* __restrict__ psum, const float* __restrict__ zlabel,
                float* __restrict__ rowloss)
{
    const int r = blockIdx.x;
    const int tid = threadIdx.x;
    float s = 0.f;
    for (int k = tid; k < NCH; k += 256)
        s += psum[(size_t)k * BATCH + r];
    #pragma unroll
    for (int d = 1; d < 64; d <<= 1) s += __shfl_xor(s, d, 64);
    __shared__ float ssh[4];
    if ((tid & 63) == 0) ssh[tid >> 6] = s;
    __syncthreads();
    if (tid == 0) {
        float t = ssh[0] + ssh[1] + ssh[2] + ssh[3];
        rowloss[r] = LN2_ * (BIGZ_ + log2f(t)) - zlabel[r];
    }
}

// ---------------------------------------------------------------------------
// Kernel 4: mean over rows
// ---------------------------------------------------------------------------
__global__ __launch_bounds__(512)
void arc_mean(const float* __restrict__ rowloss, float* __restrict__ out)
{
    const int tid = threadIdx.x;
    float v = rowloss[tid];
    #pragma unroll
    for (int d = 1; d < 64; d <<= 1) v += __shfl_xor(v, d, 64);
    __shared__ float sv[8];
    if ((tid & 63) == 0) sv[tid >> 6] = v;
    __syncthreads();
    if (tid == 0) {
        float t = 0.f;
        #pragma unroll
        for (int w = 0; w < 8; ++w) t += sv[w];
        out[0] = t / (float)BATCH;
    }
}

// ===========================================================================
// FALLBACK (small-workspace) path: round-3 fused kernel, known good @145us.
// ===========================================================================
__global__ __launch_bounds__(512, 4)
void arc_fused(const ushort* __restrict__ eP, const int* __restrict__ labels,
               const float* __restrict__ weight,
               float* __restrict__ pmax, float* __restrict__ psum,
               float* __restrict__ zlabel)
{
    __shared__ ushort Wl[CT * EMBED];
    __shared__ int    labL[BATCH];

    const int tid = threadIdx.x;
    const int blk = blockIdx.x;
    const int c0  = blk * CT;

    labL[tid] = labels[tid];

    const int c = tid >> 3, p = tid & 7;
    const bool valid = (c0 + c) < C_CLASSES;
    const float4* wrow = (const float4*)(weight + (size_t)(c0 + c) * EMBED);
    float ss = 0.f;
    #pragma unroll
    for (int i = 0; i < 12; ++i) {
        float4 v = valid ? wrow[p + 8 * i] : make_float4(0.f, 0.f, 0.f, 0.f);
        ss += v.x * v.x + v.y * v.y + v.z * v.z + v.w * v.w;
    }
    #pragma unroll
    for (int d = 1; d < 8; d <<= 1) ss += __shfl_xor(ss, d, 64);
    const float inv = (valid && ss > 0.f) ? rsqrtf(ss) : 0.f;

    #pragma unroll
    for (int i = 0; i < 12; ++i) {
        float4 v = valid ? wrow[p + 8 * i] : make_float4(0.f, 0.f, 0.f, 0.f);
        int q   = p + 8 * i;
        int idx = c * EMBED + q * 4;
        int sw  = idx ^ ((c & 7) << 3);
        ushort4 o;
        o.x = f2bf(v.x * inv); o.y = f2bf(v.y * inv);
        o.z = f2bf(v.z * inv); o.w = f2bf(v.w * inv);
        *(ushort4*)&Wl[sw] = o;
    }
    __syncthreads();

    const int wid = tid >> 6, l = tid & 63;
    const int lr = l & 15, lg = l >> 4;
    const int mbase = wid * 64;

    f32x4 acc[4][4];
    #pragma unroll
    for (int mt = 0; mt < 4; ++mt)
        #pragma unroll
        for (int nt = 0; nt < 4; ++nt)
            acc[mt][nt] = (f32x4){0.f, 0.f, 0.f, 0.f};

    const ushort* abase = eP + ((size_t)(wid * 4) * 12 * 64 + l) * 8;

    #pragma unroll
    for (int ks = 0; ks < 12; ++ks) {
        bf16x8 a[4], b[4];
        #pragma unroll
        for (int mt = 0; mt < 4; ++mt)
            a[mt] = *(const bf16x8*)(abase + (mt * 12 + ks) * 512);
        #pragma unroll
        for (int nt = 0; nt < 4; ++nt) {
            int cc  = nt * 16 + lr;
            int idx = cc * EMBED + ks * 32 + lg * 8;
            b[nt] = *(const bf16x8*)&Wl[idx ^ ((cc & 7) << 3)];
        }
        #pragma unroll
        for (int mt = 0; mt < 4; ++mt)
            #pragma unroll
            for (int nt = 0; nt < 4; ++nt)
                acc[mt][nt] = __builtin_amdgcn_mfma_f32_16x16x32_bf16(
                    a[mt], b[nt], acc[mt][nt], 0, 0, 0);
    }

    #pragma unroll
    for (int mt = 0; mt < 4; ++mt) {
        #pragma unroll
        for (int rg = 0; rg < 4; ++rg) {
            int r   = mbase + mt * 16 + lg * 4 + rg;
            int lab = labL[r];
            float z[4];
            #pragma unroll
            for (int nt = 0; nt < 4; ++nt) {
                int gc = c0 + nt * 16 + lr;
                float cosv = acc[mt][nt][rg];
                cosv = fminf(fmaxf(cosv, -1.f + EPS_), 1.f - EPS_);
                float zz = S_SCALE * cosv;
                if (gc == lab) {
                    float zm;
                    if (cosv > TH_) {
                        float sv = sqrtf(fmaxf(1.f - cosv * cosv, 0.f));
                        zm = S_SCALE * (cosv * COS_M_ - sv * SIN_M_);
                    } else {
                        zm = S_SCALE * (cosv - MM_);
                    }
                    zlabel[r] = zm;
                    zz = zm;
                }
                z[nt] = (gc >= C_CLASSES) ? -1e30f : zz * LOG2E_;
            }
            float m = fmaxf(fmaxf(z[0], z[1]), fmaxf(z[2], z[3]));
            #pragma unroll
            for (int d = 1; d < 16; d <<= 1) m = fmaxf(m, __shfl_xor(m, d, 64));
            float s = 0.f;
            #pragma unroll
            for (int nt = 0; nt < 4; ++nt) s += exp2f(z[nt] - m);
            #pragma unroll
            for (int d = 1; d < 16; d <<= 1) s += __shfl_xor(s, d, 64);
            if (lr == 0) {
                pmax[(size_t)r * NCH + blk] = m;
                psum[(size_t)r * NCH + blk] = s;
            }
        }
    }
}

__global__ __launch_bounds__(256)
void arc_reduce_m(const float* __restrict__ pmax, const float* __restrict__ psum,
                  const float* __restrict__ zlabel, float* __restrict__ rowloss)
{
    const int r = blockIdx.x;
    const int tid = threadIdx.x;
    float m = -1e30f, s = 0.f;
    for (int k = tid; k < NCH; k += 256) {
        float m2 = pmax[(size_t)r * NCH + k];
        float s2 = psum[(size_t)r * NCH + k];
        float M = fmaxf(m, m2);
        s = s * exp2f(m - M) + s2 * exp2f(m2 - M);
        m = M;
    }
    #pragma unroll
    for (int d = 1; d < 64; d <<= 1) {
        float m2 = __shfl_xor(m, d, 64);
        float s2 = __shfl_xor(s, d, 64);
        float M = fmaxf(m, m2);
        s = s * exp2f(m - M) + s2 * exp2f(m2 - M);
        m = M;
    }
    __shared__ float sm[4], ssh[4];
    if ((tid & 63) == 0) { sm[tid >> 6] = m; ssh[tid >> 6] = s; }
    __syncthreads();
    if (tid == 0) {
        m = sm[0]; s = ssh[0];
        #pragma unroll
        for (int w = 1; w < 4; ++w) {
            float M = fmaxf(m, sm[w]);
            s = s * exp2f(m - M) + ssh[w] * exp2f(sm[w] - M);
            m = M;
        }
        rowloss[r] = LN2_ * (m + log2f(s)) - zlabel[r];
    }
}

extern "C" void kernel_launch(void* const* d_in, const int* in_sizes, int n_in,
                              void* d_out, int out_size, void* d_ws, size_t ws_size,
                              hipStream_t stream)
{
    (void)in_sizes; (void)n_in; (void)out_size;
    const float* emb    = (const float*)d_in[0];
    const int*   labels = (const int*)d_in[1];
    const float* weight = (const float*)d_in[2];
    float* out = (float*)d_out;

    // main-path workspace layout
    const size_t psum_elems = (size_t)NCH * BATCH;         // 800,256
    const size_t eP_elems   = (size_t)BATCH * EMBED;       // 196,608 ushorts
    const size_t wB_elems   = (size_t)WTILES * 12 * 512;   // 38,412,288 ushorts

    float*  psum    = (float*)d_ws;
    float*  zlabel  = psum + psum_elems;
    float*  rowloss = zlabel + BATCH;
    ushort* eP      = (ushort*)(rowloss + BATCH);
    ushort* wB      = eP + eP_elems;
    const size_t need = (char*)(wB + wB_elems) - (char*)d_ws;

    if (ws_size >= need) {
        cvt_pack_e<<<(BATCH * EMBED / 8) / 256, 256, 0, stream>>>(emb, eP);
        norm_pack_w<<<C_CLASSES / 16, 256, 0, stream>>>(weight, wB);
        arc_gemm<<<NCH, 512, 0, stream>>>(eP, wB, labels, psum, zlabel);
        arc_reduce<<<BATCH, 256, 0, stream>>>(psum, zlabel, rowloss);
        arc_mean<<<1, 512, 0, stream>>>(rowloss, out);
    } else {
        // fallback: fused round-3 path (~13.6 MB workspace)
        float*  pmaxF    = (float*)d_ws;                       // [BATCH][NCH]
        float*  psumF    = pmaxF + psum_elems;                 // [BATCH][NCH]
        float*  zlabelF  = psumF + psum_elems;
        float*  rowlossF = zlabelF + BATCH;
        ushort* ePF      = (ushort*)(rowlossF + BATCH);
        cvt_pack_e<<<(BATCH * EMBED / 8) / 256, 256, 0, stream>>>(emb, ePF);
        arc_fused<<<NCH, 512, 0, stream>>>(ePF, labels, weight,
                                           pmaxF, psumF, zlabelF);
        arc_reduce_m<<<BATCH, 256, 0, stream>>>(pmaxF, psumF, zlabelF, rowlossF);
        arc_mean<<<1, 512, 0, stream>>>(rowlossF, out);
    }
}